// Round 11
// baseline (151.350 us; speedup 1.0000x reference)
//
#include <hip/hip_runtime.h>
#include <cstdint>

typedef float f32x4 __attribute__((ext_vector_type(4)));
typedef long longx2 __attribute__((ext_vector_type(2)));
typedef unsigned char u8;
typedef unsigned short u16;
typedef unsigned int u32;
typedef unsigned long long u64;

#define B_N 8
#define T_N 2048
#define D_N 512
#define TAU 5.0f
#define NROW (B_N * T_N)    // 16384
// exp(TAU*s - 1) == exp2(K1*s - K2)
#define K1E 7.213475204444817f
#define K2E 1.4426950408889634f

__device__ __forceinline__ void gload_lds16(const u8* g, u8* l) {
  __builtin_amdgcn_global_load_lds(
      (const __attribute__((address_space(1))) u32*)g,
      (__attribute__((address_space(3))) u32*)l, 16, 0, 0);
}

// pack 4 floats -> 4 fp8(e4m3) bytes in a u32
__device__ __forceinline__ u32 pk4_fp8(float a, float b, float c, float d) {
  int w = __builtin_amdgcn_cvt_pk_fp8_f32(a, b, 0, 0);
  w = __builtin_amdgcn_cvt_pk_fp8_f32(c, d, w, 1);
  return (u32)w;
}

__device__ __forceinline__ u16 f2bf16(float x) {   // RNE f32->bf16
  u32 u = __builtin_bit_cast(u32, x);
  u32 r = u + 0x7fffu + ((u >> 16) & 1u);
  return (u16)(r >> 16);
}
__device__ __forceinline__ float bf2f(u16 v) {
  u32 u = ((u32)v) << 16;
  return __builtin_bit_cast(float, u);
}

// ---------------- k1: normalize E rows, emit fp8 in b128-PAIR fragment order.
// EF2: addr = j*2048 + tok*64 + g*16 + h*8 + e -> E[tok][(2j+h)*32 + g*8 + e]
// ET2 (token-PERMUTED, sigma(8g+j) = 4g+j / 16+4g+(j-4)):
//      addr = m*1024 + g*256 + c*16 + h*8 + e ->
//        lo-word toks 4g..4g+3, hi-word toks 16+4g..16+4g+3, d=(2m+h)*16+c
__global__ void kprep(const float* __restrict__ text,
                      u8* __restrict__ EF, u8* __restrict__ ET) {
  __shared__ u8 tile[32][528];
  int b = blockIdx.y, t = blockIdx.x;
  int tr = threadIdx.x;
  int row = tr >> 3, seg = tr & 7;          // 32 rows x 8 segs of 64 d
  const float* src = text + ((size_t)b * T_N + t * 32 + row) * D_N + seg * 64;
  float4 v[16];
  float ss = 0.f;
#pragma unroll
  for (int j = 0; j < 16; ++j) {
    v[j] = *(const float4*)(src + j * 4);
    ss += v[j].x*v[j].x + v[j].y*v[j].y + v[j].z*v[j].z + v[j].w*v[j].w;
  }
  ss += __shfl_xor(ss, 1); ss += __shfl_xor(ss, 2); ss += __shfl_xor(ss, 4);
  float inv = 1.f / fmaxf(sqrtf(ss), 1e-12f);
  u32 w[16];
#pragma unroll
  for (int j = 0; j < 16; ++j)
    w[j] = pk4_fp8(v[j].x*inv, v[j].y*inv, v[j].z*inv, v[j].w*inv);
  uint4* ldst = (uint4*)&tile[row][seg * 64];
#pragma unroll
  for (int j = 0; j < 4; ++j)
    ldst[j] = make_uint4(w[4*j], w[4*j+1], w[4*j+2], w[4*j+3]);
  __syncthreads();
  size_t tbase = ((size_t)(b * 64 + t)) << 14;
  {
    // EF2: thread covers 64B: j = tr>>5, tok = tr&31
    int j = tr >> 5, tok = tr & 31;
    u32 acc[16];
#pragma unroll
    for (int g2 = 0; g2 < 4; ++g2)
#pragma unroll
      for (int h = 0; h < 2; ++h) {
        uint2 vv = *(const uint2*)&tile[tok][j*64 + h*32 + g2*8];
        acc[g2*4 + h*2] = vv.x; acc[g2*4 + h*2 + 1] = vv.y;
      }
    uint4* dst = (uint4*)(EF + tbase + tr * 64);
#pragma unroll
    for (int q = 0; q < 4; ++q)
      dst[q] = make_uint4(acc[4*q], acc[4*q+1], acc[4*q+2], acc[4*q+3]);
  }
  {
    // ET2 (sigma-permuted): thread covers 64B: m = tr>>4, g = (tr>>2)&3, c0 = (tr&3)*4
    int m = tr >> 4, g2 = (tr >> 2) & 3, c0 = (tr & 3) * 4;
    u32 acc[16];
#pragma unroll
    for (int ci = 0; ci < 4; ++ci)
#pragma unroll
      for (int h = 0; h < 2; ++h) {
        int c = c0 + ci, n = 2*m + h;
        u32 lo = 0, hi = 0;
#pragma unroll
        for (int e = 0; e < 4; ++e) lo |= (u32)tile[g2*4 + e][n*16 + c] << (8*e);
#pragma unroll
        for (int e = 0; e < 4; ++e) hi |= (u32)tile[16 + g2*4 + e][n*16 + c] << (8*e);
        acc[ci*4 + h*2] = lo; acc[ci*4 + h*2 + 1] = hi;
      }
    uint4* dst = (uint4*)(ET + tbase + tr * 64);
#pragma unroll
    for (int q = 0; q < 4; ++q)
      dst[q] = make_uint4(acc[4*q], acc[4*q+1], acc[4*q+2], acc[4*q+3]);
  }
}

// ---------------- k2: flash attention over a column HALF.
// Stream-split: S-phase E-frags read DIRECTLY from global (L1/L2-resident,
// 16KB tile, 4x block reuse) -> LDS carries only the PV ET stream.
// T15 pipeline: S(t+1) MFMAs issued alongside softmax(t)+PV(t) (independent).
// Math identical to rounds 8-10. ----
__launch_bounds__(256, 2)
__global__ void kflash(const float* __restrict__ pred,
                       const u8* __restrict__ EF, const u8* __restrict__ ET,
                       const int* __restrict__ mask,
                       u16* __restrict__ Opart, float* __restrict__ Lpart) {
  int b = blockIdx.x & 7;                 // batch -> XCD pin
  int rem = blockIdx.x >> 3;
  int rb = rem & 31, h = rem >> 5;        // row-block, column half
  int wid = threadIdx.x >> 6, lane = threadIdx.x & 63;
  int g = lane >> 4, c = lane & 15;
  int row0 = rb * 64 + wid * 16;
  int t0 = h * 32;

  __shared__ u64 mbits[32];
  __shared__ __align__(16) u8 etls[2][16384];   // PV stream only (2 x 16KB)

  const int sb_off = c * 64 + g * 16;      // S-phase A-frag lane offset
  const int pv_off = g * 256 + c * 16;     // PV-phase B-frag lane offset

  const u8* EFl = EF + (((size_t)(b * 64 + t0)) << 14) + sb_off;  // per-lane
  const u8* ETb = ET + (((size_t)(b * 64)) << 14) + (lane << 4);

  auto stage = [&](int buf, int t) {       // 4 gload_lds per wave (ET only)
    size_t tb = ((size_t)t) << 14;
#pragma unroll
    for (int j = 0; j < 4; ++j) {
      int ch = j * 4 + wid;
      gload_lds16(ETb + tb + (ch << 10), &etls[buf][ch << 10]);
    }
  };

  for (int chunk = wid; chunk < 32; chunk += 4) {
    int col = chunk * 64 + lane;
    u64 bal = __ballot(mask[b * T_N + col] == 0);  // True mask = PAD
    if (lane == 0) mbits[chunk] = bal;
  }

  stage(0, t0); stage(1, t0 + 1);

  // P fragments: two-pass fp32 normalize -> fp8; overlaps ET staging.
  long pf[16];
  {
    int prow = row0 + c;
    const float* pr = pred + ((size_t)(b * T_N) + prow) * D_N;
    float ss = 0.f;
#pragma unroll
    for (int kk = 0; kk < 16; ++kk) {
      float4 v0 = *(const float4*)(pr + kk * 32 + g * 8);
      float4 v1 = *(const float4*)(pr + kk * 32 + g * 8 + 4);
      ss += v0.x*v0.x + v0.y*v0.y + v0.z*v0.z + v0.w*v0.w
          + v1.x*v1.x + v1.y*v1.y + v1.z*v1.z + v1.w*v1.w;
    }
    ss += __shfl_xor(ss, 16);
    ss += __shfl_xor(ss, 32);
    float inv = 1.f / fmaxf(sqrtf(ss), 1e-12f);
#pragma unroll
    for (int kk = 0; kk < 16; ++kk) {
      float4 v0 = *(const float4*)(pr + kk * 32 + g * 8);
      float4 v1 = *(const float4*)(pr + kk * 32 + g * 8 + 4);
      u32 lo = pk4_fp8(v0.x*inv, v0.y*inv, v0.z*inv, v0.w*inv);
      u32 hi = pk4_fp8(v1.x*inv, v1.y*inv, v1.z*inv, v1.w*inv);
      pf[kk] = (long)(((u64)hi << 32) | lo);
    }
  }

  __syncthreads();   // mbits visible; tile t0/t0+1 staging drained

  f32x4 zero = {0.f, 0.f, 0.f, 0.f};
  f32x4 eh[32];
#pragma unroll
  for (int n = 0; n < 32; ++n) eh[n] = zero;
  float lsum = 0.f;                        // per-lane: q-row c partial

  // S^T = E . P^T from GLOBAL (L1/L2). tt is tile index relative to t0.
  auto scompute = [&](int tt, f32x4& s0, f32x4& s1) {
    const u8* ef = EFl + ((size_t)tt << 14);
    f32x4 ta0 = zero, tb0 = zero, ta1 = zero, tb1 = zero;
    __builtin_amdgcn_s_setprio(1);
#pragma unroll
    for (int j = 0; j < 8; ++j) {
      longx2 b0 = *(const longx2*)(ef + j * 2048);
      longx2 b1 = *(const longx2*)(ef + j * 2048 + 1024);
      ta0 = __builtin_amdgcn_mfma_f32_16x16x32_fp8_fp8(b0[0], pf[2*j],   ta0, 0, 0, 0);
      tb0 = __builtin_amdgcn_mfma_f32_16x16x32_fp8_fp8(b0[1], pf[2*j+1], tb0, 0, 0, 0);
      ta1 = __builtin_amdgcn_mfma_f32_16x16x32_fp8_fp8(b1[0], pf[2*j],   ta1, 0, 0, 0);
      tb1 = __builtin_amdgcn_mfma_f32_16x16x32_fp8_fp8(b1[1], pf[2*j+1], tb1, 0, 0, 0);
    }
    __builtin_amdgcn_s_setprio(0);
    s0 = ta0 + tb0; s1 = ta1 + tb1;        // s0: toks g*4+r, s1: 16+g*4+r (qrow c)
  };

  f32x4 s0c, s1c, s0n, s1n;
  scompute(0, s0c, s1c);                   // prologue: S(tile 0)

#pragma unroll 1
  for (int tt = 0; tt < 32; ++tt) {
    // S(t+1): independent of softmax(t)/PV(t) -> MFMA pipe stays fed while
    // VALU finishes tile t. (T15)
    if (tt + 1 < 32) scompute(tt + 1, s0n, s1n);

    // softmax(t): fixed-max exp2, mask bits
    int c0 = (t0 + tt) * 32;
    u64 mw = mbits[c0 >> 6];
    u32 sh0 = (c0 & 63) + g * 4;
    u32 bits0 = (u32)(mw >> sh0) & 0xf;
    u32 bits1 = (u32)(mw >> (sh0 + 16)) & 0xf;
    float p0[4], p1[4];
#pragma unroll
    for (int r = 0; r < 4; ++r) {
      p0[r] = (bits0 >> r) & 1 ? __builtin_exp2f(fmaf(K1E, s0c[r], -K2E)) : 0.f;
      p1[r] = (bits1 >> r) & 1 ? __builtin_exp2f(fmaf(K1E, s1c[r], -K2E)) : 0.f;
      lsum += p0[r] + p1[r];
    }
    // sigma-permuted ET: A-frag = (own lo, own hi). No shuffles.
    u32 lo = pk4_fp8(p0[0], p0[1], p0[2], p0[3]);  // toks 4g..4g+3
    u32 hi = pk4_fp8(p1[0], p1[1], p1[2], p1[3]);  // toks 16+4g..16+4g+3
    long af = (long)(((u64)hi << 32) | lo);

    // PV(t) from LDS
    const u8* et = &etls[tt & 1][0];
    __builtin_amdgcn_s_setprio(1);
#pragma unroll
    for (int m = 0; m < 16; ++m) {
      longx2 bv = *(const longx2*)(et + m * 1024 + pv_off);
      eh[2*m]   = __builtin_amdgcn_mfma_f32_16x16x32_fp8_fp8(af, bv[0], eh[2*m],   0, 0, 0);
      eh[2*m+1] = __builtin_amdgcn_mfma_f32_16x16x32_fp8_fp8(af, bv[1], eh[2*m+1], 0, 0, 0);
    }
    __builtin_amdgcn_s_setprio(0);
    __syncthreads();                       // all waves done reading etls[tt&1]
    if (tt < 30) stage(tt & 1, t0 + tt + 2);
    s0c = s0n; s1c = s1n;
  }

  // partial outputs: l (reduce over g-groups; row = c), O (bf16)
  lsum += __shfl_xor(lsum, 16);
  lsum += __shfl_xor(lsum, 32);
  u16* OP = Opart + (size_t)h * ((size_t)NROW * D_N);
#pragma unroll
  for (int r = 0; r < 4; ++r) {
    int brow = b * T_N + row0 + g * 4 + r;
    u16* orow = OP + (size_t)brow * D_N + c;
#pragma unroll
    for (int n = 0; n < 32; ++n) orow[n * 16] = f2bf16(eh[n][r]);
  }
  if (g == 0) {
    Lpart[h * NROW + b * T_N + row0 + c] = lsum;
  }
}

// ---------------- k3: merge halves + cosine + per-block partial sums ----------------
__global__ void kcomb(const float* __restrict__ pred, const u16* __restrict__ Opart,
                      const float* __restrict__ Lpart,
                      float* __restrict__ pl, float* __restrict__ pw) {
  __shared__ float sl[8], swv[8];
  int tr = threadIdx.x;
  int row = blockIdx.x * 8 + (tr >> 5);
  int ln = tr & 31;
  float l = Lpart[row] + Lpart[NROW + row];
  const float* pr = pred + (size_t)row * D_N + ln * 16;
  const u16* o0 = Opart + (size_t)row * D_N + ln * 16;
  const u16* o1 = o0 + (size_t)NROW * D_N;
  float dot = 0.f, e2 = 0.f, pn2 = 0.f;
#pragma unroll
  for (int q = 0; q < 2; ++q) {
    uint4 a0 = *(const uint4*)(o0 + q * 8);
    uint4 a1 = *(const uint4*)(o1 + q * 8);
    u32 w0[4] = {a0.x, a0.y, a0.z, a0.w};
    u32 w1[4] = {a1.x, a1.y, a1.z, a1.w};
    float4 p0 = *(const float4*)(pr + q * 8);
    float4 p1 = *(const float4*)(pr + q * 8 + 4);
    float pp[8] = {p0.x, p0.y, p0.z, p0.w, p1.x, p1.y, p1.z, p1.w};
#pragma unroll
    for (int j = 0; j < 8; ++j) {
      float f0 = bf2f((u16)((w0[j >> 1] >> ((j & 1) * 16)) & 0xffff));
      float f1 = bf2f((u16)((w1[j >> 1] >> ((j & 1) * 16)) & 0xffff));
      float ev = f0 + f1;
      dot += pp[j] * ev;
      e2 += ev * ev;
      pn2 += pp[j] * pp[j];
    }
  }
#pragma unroll
  for (int msk = 16; msk >= 1; msk >>= 1) {
    dot += __shfl_xor(dot, msk);
    e2 += __shfl_xor(e2, msk);
    pn2 += __shfl_xor(pn2, msk);
  }
  if (ln == 0) {
    float w = (l > 0.f) ? 1.f : 0.f;
    float pn = fmaxf(sqrtf(pn2), 1e-12f);
    float denom = pn * fmaxf(sqrtf(e2), 1e-8f * l);
    float cosv = (l > 0.f) ? dot / denom : 0.f;
    sl[tr >> 5] = w * (1.f - cosv);
    swv[tr >> 5] = w;
  }
  __syncthreads();
  if (tr == 0) {
    float a = 0.f, b2 = 0.f;
#pragma unroll
    for (int i = 0; i < 8; ++i) { a += sl[i]; b2 += swv[i]; }
    pl[blockIdx.x] = a;
    pw[blockIdx.x] = b2;
  }
}

// ---------------- k4: deterministic final reduction (2048 partials) ----------------
__global__ void kreduce(const float* __restrict__ pl, const float* __restrict__ pw,
                        float* __restrict__ out) {
  __shared__ float sm[256], sw[256];
  float s = 0.f, w = 0.f;
  for (int i = threadIdx.x; i < NROW / 8; i += 256) { s += pl[i]; w += pw[i]; }
  sm[threadIdx.x] = s; sw[threadIdx.x] = w;
  __syncthreads();
#pragma unroll
  for (int st = 128; st >= 1; st >>= 1) {
    if ((int)threadIdx.x < st) {
      sm[threadIdx.x] += sm[threadIdx.x + st];
      sw[threadIdx.x] += sw[threadIdx.x + st];
    }
    __syncthreads();
  }
  if (threadIdx.x == 0) {
    float cnt = sw[0];
    float loss = (cnt > 0.f) ? sm[0] / fmaxf(cnt, 1.f) : 0.f;
    out[0] = loss;
    out[1] = (cnt > 0.f) ? 1.f - loss : 0.f;
  }
}

extern "C" void kernel_launch(void* const* d_in, const int* in_sizes, int n_in,
                              void* d_out, int out_size, void* d_ws, size_t ws_size,
                              hipStream_t stream) {
  const float* pred = (const float*)d_in[0];
  const float* text = (const float*)d_in[1];
  const int* mask = (const int*)d_in[2];
  char* ws = (char*)d_ws;
  const size_t EB8 = (size_t)B_N * T_N * D_N;          // 8MB per fp8 tensor
  const size_t OB = (size_t)NROW * D_N * 2;            // 16MB per bf16 O-half
  u8* EF = (u8*)ws;
  u8* ET = (u8*)(ws + EB8);
  u16* Opart = (u16*)(ws + 2 * EB8);                   // 2 halves = 32MB
  float* Lpart = (float*)(ws + 2 * EB8 + 2 * OB);      // 2*64KB
  float* pl = (float*)(ws + 2 * EB8 + 2 * OB + 131072);
  float* pw = (float*)(ws + 2 * EB8 + 2 * OB + 131072 + 16384);
  float* out = (float*)d_out;

  kprep<<<dim3(64, 8), dim3(256), 0, stream>>>(text, EF, ET);
  kflash<<<dim3(512), dim3(256), 0, stream>>>(pred, EF, ET, mask, Opart, Lpart);
  kcomb<<<dim3(NROW / 8), dim3(256), 0, stream>>>(pred, Opart, Lpart, pl, pw);
  kreduce<<<dim3(1), dim3(256), 0, stream>>>(pl, pw, out);
}

// Round 12
// 103.499 us; speedup vs baseline: 1.4623x; 1.4623x over previous
//
#include <hip/hip_runtime.h>
#include <cstdint>

typedef float f32x4 __attribute__((ext_vector_type(4)));
typedef long longx2 __attribute__((ext_vector_type(2)));
typedef unsigned char u8;
typedef unsigned short u16;
typedef unsigned int u32;
typedef unsigned long long u64;

#define B_N 8
#define T_N 2048
#define D_N 512
#define TAU 5.0f
#define NROW (B_N * T_N)    // 16384
// exp(TAU*s - 1) == exp2(K1*s - K2)
#define K1E 7.213475204444817f
#define K2E 1.4426950408889634f

#define WAITV(n) asm volatile("s_waitcnt vmcnt(" #n ")" ::: "memory")
#define BAR      __builtin_amdgcn_s_barrier()

__device__ __forceinline__ void gload_lds16(const u8* g, u8* l) {
  __builtin_amdgcn_global_load_lds(
      (const __attribute__((address_space(1))) u32*)g,
      (__attribute__((address_space(3))) u32*)l, 16, 0, 0);
}

// pack 4 floats -> 4 fp8(e4m3) bytes in a u32
__device__ __forceinline__ u32 pk4_fp8(float a, float b, float c, float d) {
  int w = __builtin_amdgcn_cvt_pk_fp8_f32(a, b, 0, 0);
  w = __builtin_amdgcn_cvt_pk_fp8_f32(c, d, w, 1);
  return (u32)w;
}

__device__ __forceinline__ u16 f2bf16(float x) {   // RNE f32->bf16
  u32 u = __builtin_bit_cast(u32, x);
  u32 r = u + 0x7fffu + ((u >> 16) & 1u);
  return (u16)(r >> 16);
}
__device__ __forceinline__ float bf2f(u16 v) {
  u32 u = ((u32)v) << 16;
  return __builtin_bit_cast(float, u);
}

// ---------------- k1: normalize E rows, emit fp8 in b128-PAIR fragment order.
// EF2: addr = j*2048 + tok*64 + g*16 + h*8 + e -> E[tok][(2j+h)*32 + g*8 + e]
// ET2 (token-PERMUTED, sigma(8g+j) = 4g+j / 16+4g+(j-4)):
//      addr = m*1024 + g*256 + c*16 + h*8 + e ->
//        lo-word toks 4g..4g+3, hi-word toks 16+4g..16+4g+3, d=(2m+h)*16+c
__global__ void kprep(const float* __restrict__ text,
                      u8* __restrict__ EF, u8* __restrict__ ET) {
  __shared__ u8 tile[32][528];
  int b = blockIdx.y, t = blockIdx.x;
  int tr = threadIdx.x;
  int row = tr >> 3, seg = tr & 7;          // 32 rows x 8 segs of 64 d
  const float* src = text + ((size_t)b * T_N + t * 32 + row) * D_N + seg * 64;
  float4 v[16];
  float ss = 0.f;
#pragma unroll
  for (int j = 0; j < 16; ++j) {
    v[j] = *(const float4*)(src + j * 4);
    ss += v[j].x*v[j].x + v[j].y*v[j].y + v[j].z*v[j].z + v[j].w*v[j].w;
  }
  ss += __shfl_xor(ss, 1); ss += __shfl_xor(ss, 2); ss += __shfl_xor(ss, 4);
  float inv = 1.f / fmaxf(sqrtf(ss), 1e-12f);
  u32 w[16];
#pragma unroll
  for (int j = 0; j < 16; ++j)
    w[j] = pk4_fp8(v[j].x*inv, v[j].y*inv, v[j].z*inv, v[j].w*inv);
  uint4* ldst = (uint4*)&tile[row][seg * 64];
#pragma unroll
  for (int j = 0; j < 4; ++j)
    ldst[j] = make_uint4(w[4*j], w[4*j+1], w[4*j+2], w[4*j+3]);
  __syncthreads();
  size_t tbase = ((size_t)(b * 64 + t)) << 14;
  {
    // EF2: thread covers 64B: j = tr>>5, tok = tr&31
    int j = tr >> 5, tok = tr & 31;
    u32 acc[16];
#pragma unroll
    for (int g2 = 0; g2 < 4; ++g2)
#pragma unroll
      for (int h = 0; h < 2; ++h) {
        uint2 vv = *(const uint2*)&tile[tok][j*64 + h*32 + g2*8];
        acc[g2*4 + h*2] = vv.x; acc[g2*4 + h*2 + 1] = vv.y;
      }
    uint4* dst = (uint4*)(EF + tbase + tr * 64);
#pragma unroll
    for (int q = 0; q < 4; ++q)
      dst[q] = make_uint4(acc[4*q], acc[4*q+1], acc[4*q+2], acc[4*q+3]);
  }
  {
    // ET2 (sigma-permuted): thread covers 64B: m = tr>>4, g = (tr>>2)&3, c0 = (tr&3)*4
    int m = tr >> 4, g2 = (tr >> 2) & 3, c0 = (tr & 3) * 4;
    u32 acc[16];
#pragma unroll
    for (int ci = 0; ci < 4; ++ci)
#pragma unroll
      for (int h = 0; h < 2; ++h) {
        int c = c0 + ci, n = 2*m + h;
        u32 lo = 0, hi = 0;
#pragma unroll
        for (int e = 0; e < 4; ++e) lo |= (u32)tile[g2*4 + e][n*16 + c] << (8*e);
#pragma unroll
        for (int e = 0; e < 4; ++e) hi |= (u32)tile[16 + g2*4 + e][n*16 + c] << (8*e);
        acc[ci*4 + h*2] = lo; acc[ci*4 + h*2 + 1] = hi;
      }
    uint4* dst = (uint4*)(ET + tbase + tr * 64);
#pragma unroll
    for (int q = 0; q < 4; ++q)
      dst[q] = make_uint4(acc[4*q], acc[4*q+1], acc[4*q+2], acc[4*q+3]);
  }
}

// ---------------- k2: flash attention, m201-style fine-phase schedule.
// 512 threads = 8 waves x 16 rows = 128 rows/block; 1 block/CU; grid 256.
// Per tile: 4 barrier-bracketed phases {stage-issue | 8 ds_read | setprio MFMA
// cluster}, counted WAITV(2) once per tile (never 0 until the last tile).
// Buffer safety: stageET(t+1)->etls[(t+1)&1] issues after the iter-top BAR
// (all waves completed P5(t-1) whose reads used that buffer); stageE(t+2)->
// els[t&1] issues after P2's BAR (all waves' E reads of tile t consumed).
// Math/fragment layouts identical to round 10. Also accumulates
// dsum = sum_s p_s * s_s  ( = dot(P_hat, O) ), so kcomb needs no pred read.
__launch_bounds__(512, 2)
__global__ void kflash(const float* __restrict__ pred,
                       const u8* __restrict__ EF, const u8* __restrict__ ET,
                       const int* __restrict__ mask,
                       u16* __restrict__ Opart, float* __restrict__ Lpart,
                       float* __restrict__ Dpart) {
  int b = blockIdx.x & 7;                 // batch -> XCD pin
  int rem = blockIdx.x >> 3;
  int rb = rem & 15, h = rem >> 4;        // 16 row-blocks of 128 rows, 2 halves
  int wid = threadIdx.x >> 6, lane = threadIdx.x & 63;
  int g = lane >> 4, c = lane & 15;
  int row0 = rb * 128 + wid * 16;
  int t0 = h * 32;

  __shared__ u64 mbits[32];
  __shared__ __align__(16) u8 els[2][16384];
  __shared__ __align__(16) u8 etls[2][16384];

  const u8* EFb = EF + (((size_t)(b * 64)) << 14) + (lane << 4);
  const u8* ETb = ET + (((size_t)(b * 64)) << 14) + (lane << 4);

  auto stageE = [&](int buf, int t) {     // 2 gload per wave, 16 chunks total
    size_t tb = ((size_t)t) << 14;
#pragma unroll
    for (int j = 0; j < 2; ++j) {
      int ch = wid * 2 + j;
      gload_lds16(EFb + tb + (ch << 10), &els[buf][ch << 10]);
    }
  };
  auto stageET = [&](int buf, int t) {
    size_t tb = ((size_t)t) << 14;
#pragma unroll
    for (int j = 0; j < 2; ++j) {
      int ch = wid * 2 + j;
      gload_lds16(ETb + tb + (ch << 10), &etls[buf][ch << 10]);
    }
  };

  for (int chunk = wid; chunk < 32; chunk += 8) {
    int col = chunk * 64 + lane;
    u64 bal = __ballot(mask[b * T_N + col] == 0);  // True mask = PAD
    if (lane == 0) mbits[chunk] = bal;
  }

  // prologue prefetch: E(t0), ET(t0), E(t0+1)
  stageE(0, t0); stageET(0, t0); stageE(1, t0 + 1);

  // P fragments: two-pass fp32 normalize -> fp8 (identical to r10)
  long pf[16];
  {
    int prow = row0 + c;
    const float* pr = pred + ((size_t)(b * T_N) + prow) * D_N;
    float ss = 0.f;
#pragma unroll
    for (int kk = 0; kk < 16; ++kk) {
      float4 v0 = *(const float4*)(pr + kk * 32 + g * 8);
      float4 v1 = *(const float4*)(pr + kk * 32 + g * 8 + 4);
      ss += v0.x*v0.x + v0.y*v0.y + v0.z*v0.z + v0.w*v0.w
          + v1.x*v1.x + v1.y*v1.y + v1.z*v1.z + v1.w*v1.w;
    }
    ss += __shfl_xor(ss, 16);
    ss += __shfl_xor(ss, 32);
    float inv = 1.f / fmaxf(sqrtf(ss), 1e-12f);
#pragma unroll
    for (int kk = 0; kk < 16; ++kk) {
      float4 v0 = *(const float4*)(pr + kk * 32 + g * 8);
      float4 v1 = *(const float4*)(pr + kk * 32 + g * 8 + 4);
      u32 lo = pk4_fp8(v0.x*inv, v0.y*inv, v0.z*inv, v0.w*inv);
      u32 hi = pk4_fp8(v1.x*inv, v1.y*inv, v1.z*inv, v1.w*inv);
      pf[kk] = (long)(((u64)hi << 32) | lo);
    }
  }

  __syncthreads();   // mbits visible; prologue staging drained (vmcnt=0 here)

  f32x4 zero = {0.f, 0.f, 0.f, 0.f};
  f32x4 eh[32];
#pragma unroll
  for (int n = 0; n < 32; ++n) eh[n] = zero;
  float lsum = 0.f, dsum = 0.f;            // per-lane: q-row c partials

  const int sb_off = c * 64 + g * 16;      // S-phase A-frag lane offset
  const int pv_off = g * 256 + c * 16;     // PV-phase B-frag lane offset

#pragma unroll 1
  for (int tt = 0; tt < 32; ++tt) {
    int cur = tt & 1;
    // outstanding here: ET(t)@P1(t-1) [2], E(t+1)@P3(t-1) [2] (when staged).
    // WAITV(2) drains ET(t) (and older E(t)); leaves E(t+1) in flight.
    if (tt < 31) { WAITV(2); } else { WAITV(0); }
    BAR;                                  // iter-top: buffers-of-t ready

    // ---- Phase 1: S j=0..3 (+ issue ET(t+1) stage) ----
    if (tt < 31) stageET(cur ^ 1, t0 + tt + 1);
    const u8* el = &els[cur][0];
    f32x4 ta0 = zero, tb0 = zero, ta1 = zero, tb1 = zero;
    __builtin_amdgcn_s_setprio(1);
#pragma unroll
    for (int j = 0; j < 4; ++j) {
      longx2 b0 = *(const longx2*)(el + j * 2048 + sb_off);
      longx2 b1 = *(const longx2*)(el + j * 2048 + 1024 + sb_off);
      ta0 = __builtin_amdgcn_mfma_f32_16x16x32_fp8_fp8(b0[0], pf[2*j],   ta0, 0, 0, 0);
      tb0 = __builtin_amdgcn_mfma_f32_16x16x32_fp8_fp8(b0[1], pf[2*j+1], tb0, 0, 0, 0);
      ta1 = __builtin_amdgcn_mfma_f32_16x16x32_fp8_fp8(b1[0], pf[2*j],   ta1, 0, 0, 0);
      tb1 = __builtin_amdgcn_mfma_f32_16x16x32_fp8_fp8(b1[1], pf[2*j+1], tb1, 0, 0, 0);
    }
    __builtin_amdgcn_s_setprio(0);
    BAR;

    // ---- Phase 2: S j=4..7 ----
    __builtin_amdgcn_s_setprio(1);
#pragma unroll
    for (int j = 4; j < 8; ++j) {
      longx2 b0 = *(const longx2*)(el + j * 2048 + sb_off);
      longx2 b1 = *(const longx2*)(el + j * 2048 + 1024 + sb_off);
      ta0 = __builtin_amdgcn_mfma_f32_16x16x32_fp8_fp8(b0[0], pf[2*j],   ta0, 0, 0, 0);
      tb0 = __builtin_amdgcn_mfma_f32_16x16x32_fp8_fp8(b0[1], pf[2*j+1], tb0, 0, 0, 0);
      ta1 = __builtin_amdgcn_mfma_f32_16x16x32_fp8_fp8(b1[0], pf[2*j],   ta1, 0, 0, 0);
      tb1 = __builtin_amdgcn_mfma_f32_16x16x32_fp8_fp8(b1[1], pf[2*j+1], tb1, 0, 0, 0);
    }
    __builtin_amdgcn_s_setprio(0);
    f32x4 st0 = ta0 + tb0, st1 = ta1 + tb1;  // st0: toks g*4+r, st1: 16+g*4+r
    BAR;                                  // all waves done with E(t) reads

    // ---- Phase 3: softmax + PV m=0..7 (+ issue E(t+2) stage) ----
    if (tt < 30) stageE(cur, t0 + tt + 2);
    int c0 = (t0 + tt) * 32;
    u64 mw = mbits[c0 >> 6];
    u32 sh0 = (c0 & 63) + g * 4;
    u32 bits0 = (u32)(mw >> sh0) & 0xf;
    u32 bits1 = (u32)(mw >> (sh0 + 16)) & 0xf;
    float p0[4], p1[4];
#pragma unroll
    for (int r = 0; r < 4; ++r) {
      p0[r] = (bits0 >> r) & 1 ? __builtin_exp2f(fmaf(K1E, st0[r], -K2E)) : 0.f;
      p1[r] = (bits1 >> r) & 1 ? __builtin_exp2f(fmaf(K1E, st1[r], -K2E)) : 0.f;
      lsum += p0[r] + p1[r];
      dsum += p0[r] * st0[r] + p1[r] * st1[r];   // dot(P_hat, O) partial
    }
    u32 lo = pk4_fp8(p0[0], p0[1], p0[2], p0[3]);  // toks 4g..4g+3
    u32 hi = pk4_fp8(p1[0], p1[1], p1[2], p1[3]);  // toks 16+4g..16+4g+3
    long af = (long)(((u64)hi << 32) | lo);

    const u8* et = &etls[cur][0];
    __builtin_amdgcn_s_setprio(1);
#pragma unroll
    for (int m = 0; m < 8; ++m) {
      longx2 bv = *(const longx2*)(et + m * 1024 + pv_off);
      eh[2*m]   = __builtin_amdgcn_mfma_f32_16x16x32_fp8_fp8(af, bv[0], eh[2*m],   0, 0, 0);
      eh[2*m+1] = __builtin_amdgcn_mfma_f32_16x16x32_fp8_fp8(af, bv[1], eh[2*m+1], 0, 0, 0);
    }
    __builtin_amdgcn_s_setprio(0);
    BAR;

    // ---- Phase 4: PV m=8..15 ----
    __builtin_amdgcn_s_setprio(1);
#pragma unroll
    for (int m = 8; m < 16; ++m) {
      longx2 bv = *(const longx2*)(et + m * 1024 + pv_off);
      eh[2*m]   = __builtin_amdgcn_mfma_f32_16x16x32_fp8_fp8(af, bv[0], eh[2*m],   0, 0, 0);
      eh[2*m+1] = __builtin_amdgcn_mfma_f32_16x16x32_fp8_fp8(af, bv[1], eh[2*m+1], 0, 0, 0);
    }
    __builtin_amdgcn_s_setprio(0);
    // ET(t) reads consumed; next iter-top BAR covers the cross-wave hazard.
  }

  // partial outputs: l, d (reduce over g-groups; row = c), O (bf16)
  lsum += __shfl_xor(lsum, 16);
  lsum += __shfl_xor(lsum, 32);
  dsum += __shfl_xor(dsum, 16);
  dsum += __shfl_xor(dsum, 32);
  u16* OP = Opart + (size_t)h * ((size_t)NROW * D_N);
#pragma unroll
  for (int r = 0; r < 4; ++r) {
    int brow = b * T_N + row0 + g * 4 + r;
    u16* orow = OP + (size_t)brow * D_N + c;
#pragma unroll
    for (int n = 0; n < 32; ++n) orow[n * 16] = f2bf16(eh[n][r]);
  }
  if (g == 0) {
    Lpart[h * NROW + b * T_N + row0 + c] = lsum;
    Dpart[h * NROW + b * T_N + row0 + c] = dsum;
  }
}

// ---------------- k3: merge halves + cosine (no pred read) + block partials ----
__global__ void kcomb(const u16* __restrict__ Opart, const float* __restrict__ Lpart,
                      const float* __restrict__ Dpart,
                      float* __restrict__ pl, float* __restrict__ pw) {
  __shared__ float sl[8], swv[8];
  int tr = threadIdx.x;
  int row = blockIdx.x * 8 + (tr >> 5);
  int ln = tr & 31;
  float l = Lpart[row] + Lpart[NROW + row];
  float dot = Dpart[row] + Dpart[NROW + row];
  const u16* o0 = Opart + (size_t)row * D_N + ln * 16;
  const u16* o1 = o0 + (size_t)NROW * D_N;
  float e2 = 0.f;
#pragma unroll
  for (int q = 0; q < 2; ++q) {
    uint4 a0 = *(const uint4*)(o0 + q * 8);
    uint4 a1 = *(const uint4*)(o1 + q * 8);
    u32 w0[4] = {a0.x, a0.y, a0.z, a0.w};
    u32 w1[4] = {a1.x, a1.y, a1.z, a1.w};
#pragma unroll
    for (int j = 0; j < 8; ++j) {
      float f0 = bf2f((u16)((w0[j >> 1] >> ((j & 1) * 16)) & 0xffff));
      float f1 = bf2f((u16)((w1[j >> 1] >> ((j & 1) * 16)) & 0xffff));
      float ev = f0 + f1;
      e2 += ev * ev;
    }
  }
#pragma unroll
  for (int msk = 16; msk >= 1; msk >>= 1) e2 += __shfl_xor(e2, msk);
  if (ln == 0) {
    float w = (l > 0.f) ? 1.f : 0.f;
    float cosv = (l > 0.f) ? dot / fmaxf(sqrtf(e2), 1e-8f * l) : 0.f;
    sl[tr >> 5] = w * (1.f - cosv);
    swv[tr >> 5] = w;
  }
  __syncthreads();
  if (tr == 0) {
    float a = 0.f, b2 = 0.f;
#pragma unroll
    for (int i = 0; i < 8; ++i) { a += sl[i]; b2 += swv[i]; }
    pl[blockIdx.x] = a;
    pw[blockIdx.x] = b2;
  }
}

// ---------------- k4: deterministic final reduction (2048 partials) ----------------
__global__ void kreduce(const float* __restrict__ pl, const float* __restrict__ pw,
                        float* __restrict__ out) {
  __shared__ float sm[256], sw[256];
  float s = 0.f, w = 0.f;
  for (int i = threadIdx.x; i < NROW / 8; i += 256) { s += pl[i]; w += pw[i]; }
  sm[threadIdx.x] = s; sw[threadIdx.x] = w;
  __syncthreads();
#pragma unroll
  for (int st = 128; st >= 1; st >>= 1) {
    if ((int)threadIdx.x < st) {
      sm[threadIdx.x] += sm[threadIdx.x + st];
      sw[threadIdx.x] += sw[threadIdx.x + st];
    }
    __syncthreads();
  }
  if (threadIdx.x == 0) {
    float cnt = sw[0];
    float loss = (cnt > 0.f) ? sm[0] / fmaxf(cnt, 1.f) : 0.f;
    out[0] = loss;
    out[1] = (cnt > 0.f) ? 1.f - loss : 0.f;
  }
}

extern "C" void kernel_launch(void* const* d_in, const int* in_sizes, int n_in,
                              void* d_out, int out_size, void* d_ws, size_t ws_size,
                              hipStream_t stream) {
  const float* pred = (const float*)d_in[0];
  const float* text = (const float*)d_in[1];
  const int* mask = (const int*)d_in[2];
  char* ws = (char*)d_ws;
  const size_t EB8 = (size_t)B_N * T_N * D_N;          // 8MB per fp8 tensor
  const size_t OB = (size_t)NROW * D_N * 2;            // 16MB per bf16 O-half
  u8* EF = (u8*)ws;
  u8* ET = (u8*)(ws + EB8);
  u16* Opart = (u16*)(ws + 2 * EB8);                   // 2 halves = 32MB
  char* base2 = ws + 2 * EB8 + 2 * OB;
  float* Lpart = (float*)(base2);                      // 2*64KB
  float* Dpart = (float*)(base2 + 131072);             // 2*64KB
  float* pl = (float*)(base2 + 262144);
  float* pw = (float*)(base2 + 262144 + 16384);
  float* out = (float*)d_out;

  kprep<<<dim3(64, 8), dim3(256), 0, stream>>>(text, EF, ET);
  kflash<<<dim3(256), dim3(512), 0, stream>>>(pred, EF, ET, mask, Opart, Lpart, Dpart);
  kcomb<<<dim3(NROW / 8), dim3(256), 0, stream>>>(Opart, Lpart, Dpart, pl, pw);
  kreduce<<<dim3(1), dim3(256), 0, stream>>>(pl, pw, out);
}